// Round 3
// baseline (5676.352 us; speedup 1.0000x reference)
//
#include <hip/hip_runtime.h>
#include <hip/hip_bf16.h>
#include <cstddef>

// EGNN on MI355X. fp32 throughout (reference is fp32; no fp32 MFMA on CDNA4 ->
// vector-ALU kernels). One thread per edge / per node; weights read through
// wave-uniform addresses (scalar loads); register-tiled 64-wide accumulators.
// BN batch statistics accumulated in fp64 (native global_atomic_add_f64).
// Degree (layer-invariant) is computed once before the layer loop.

#define HDIM 64
#define DEDIM 16

__device__ __forceinline__ float silu_f(float v) {
    // x * sigmoid(x) = x / (1 + e^-x). __expf -> v_exp_f32 path, ~1-2 ulp.
    return v / (1.0f + __expf(-v));
}

// out[c] = B[c] + sum_k in[k] * W[k*64+c], 64x64 fully unrolled (static reg indexing)
#define MM64(OUT, IN, W, B)                                                   \
    _Pragma("unroll") for (int c = 0; c < 64; ++c) OUT[c] = (B)[c];           \
    _Pragma("unroll") for (int k = 0; k < 64; ++k) {                          \
        const float tv_ = IN[k];                                              \
        _Pragma("unroll") for (int c = 0; c < 64; ++c)                        \
            OUT[c] = fmaf(tv_, (W)[k * 64 + c], OUT[c]);                      \
    }

// ---------------------------------------------------------------------------
// One-time degree count (dst is layer-invariant).
// ---------------------------------------------------------------------------
__global__ void __launch_bounds__(256) deg_count(
    const int* __restrict__ dst, float* __restrict__ dgo, int E)
{
    const int e = blockIdx.x * 256 + threadIdx.x;
    if (e < E) atomicAdd(&dgo[dst[e]], 1.0f);
}

// ---------------------------------------------------------------------------
// Edge kernel: per-edge MLP + atomic aggregation to dst.
// f = [h[src](64) | h[dst](64) | radial(1) | edge_feat(16)]  (145 rows of W1)
// ---------------------------------------------------------------------------
__global__ void __launch_bounds__(256) egnn_edge(
    const float* __restrict__ h, const float* __restrict__ x,
    const float* __restrict__ ef, const int* __restrict__ src,
    const int* __restrict__ dst,
    const float* __restrict__ W1, const float* __restrict__ B1,
    const float* __restrict__ W2, const float* __restrict__ B2,
    const float* __restrict__ C1, const float* __restrict__ CB1,
    const float* __restrict__ C2,
    float* __restrict__ hno, float* __restrict__ xso, int E)
{
    const int e = blockIdx.x * 256 + threadIdx.x;
    if (e >= E) return;
    const int s = src[e];
    const int d = dst[e];

    // geometry
    const float dx0 = x[3 * s + 0] - x[3 * d + 0];
    const float dx1 = x[3 * s + 1] - x[3 * d + 1];
    const float dx2 = x[3 * s + 2] - x[3 * d + 2];
    const float radial = dx0 * dx0 + dx1 * dx1 + dx2 * dx2;
    const float rinv = 1.0f / (sqrtf(radial) + 1e-30f);

    float acc[64];
#pragma unroll
    for (int c = 0; c < 64; ++c) acc[c] = B1[c];

    const float* hs = h + (size_t)s * HDIM;
    const float* hd = h + (size_t)d * HDIM;
    const float* efp = ef + (size_t)e * DEDIM;

    // rows 0..143 (h_src rows 0-63, h_dst rows 64-127, edge_feat rows 129-144)
    // in 8-wide chunks; radial row 128 handled separately below.
#pragma unroll 1
    for (int kb = 0; kb < 18; ++kb) {
        const float* fp = (kb < 8) ? (hs + kb * 8)
                        : (kb < 16) ? (hd + (kb - 8) * 8)
                                    : (efp + (kb - 16) * 8);
        const float4 fa = *(const float4*)fp;
        const float4 fb = *(const float4*)(fp + 4);
        const float fv[8] = {fa.x, fa.y, fa.z, fa.w, fb.x, fb.y, fb.z, fb.w};
        const float* wr = W1 + (size_t)((kb < 16) ? kb * 8 : kb * 8 + 1) * 64;
#pragma unroll
        for (int kk = 0; kk < 8; ++kk)
#pragma unroll
            for (int c = 0; c < 64; ++c)
                acc[c] = fmaf(fv[kk], wr[kk * 64 + c], acc[c]);
    }
    {   // radial row (row 128)
        const float* wr = W1 + 128 * 64;
#pragma unroll
        for (int c = 0; c < 64; ++c) acc[c] = fmaf(radial, wr[c], acc[c]);
    }

    // silu -> t1
    float t1[64];
#pragma unroll
    for (int c = 0; c < 64; ++c) t1[c] = silu_f(acc[c]);

    // t1 @ W2 + B2 -> silu -> mh
    float acc2[64];
    MM64(acc2, t1, W2, B2)
    float mh[64];
#pragma unroll
    for (int c = 0; c < 64; ++c) mh[c] = silu_f(acc2[c]);

    // mh @ C1 + CB1 -> silu -> t3
    float acc3[64];
    MM64(acc3, mh, C1, CB1)
#pragma unroll
    for (int c = 0; c < 64; ++c) acc3[c] = silu_f(acc3[c]);

    // coef = t3 . C2
    float coef = 0.0f;
#pragma unroll
    for (int c = 0; c < 64; ++c) coef = fmaf(acc3[c], C2[c], coef);

    // aggregation (atomics; dst is random -> distinct-address heavy)
    const float cr = coef * rinv;
    atomicAdd(&xso[3 * (size_t)d + 0], cr * dx0);
    atomicAdd(&xso[3 * (size_t)d + 1], cr * dx1);
    atomicAdd(&xso[3 * (size_t)d + 2], cr * dx2);
    float* hrow = hno + (size_t)d * HDIM;
#pragma unroll
    for (int c = 0; c < 64; ++c) atomicAdd(&hrow[c], mh[c]);
}

// ---------------------------------------------------------------------------
// Node kernel: hn = silu([h|h_neigh]@NW1+NB1)@NW2+NB2 ; x += x_sum/max(deg,1)
// ---------------------------------------------------------------------------
__global__ void __launch_bounds__(256) egnn_node(
    const float* __restrict__ h, const float* __restrict__ hnb,
    const float* __restrict__ xs, const float* __restrict__ dg,
    float* __restrict__ x,
    const float* __restrict__ NW1, const float* __restrict__ NB1,
    const float* __restrict__ NW2, const float* __restrict__ NB2,
    float* __restrict__ hn_out, int N)
{
    const int n = blockIdx.x * 256 + threadIdx.x;
    if (n >= N) return;

    float acc[64];
#pragma unroll
    for (int c = 0; c < 64; ++c) acc[c] = NB1[c];

    const float* hp = h + (size_t)n * HDIM;
    const float* gp = hnb + (size_t)n * HDIM;
#pragma unroll 1
    for (int kb = 0; kb < 16; ++kb) {
        const float* fp = (kb < 8) ? (hp + kb * 8) : (gp + (kb - 8) * 8);
        const float4 fa = *(const float4*)fp;
        const float4 fb = *(const float4*)(fp + 4);
        const float fv[8] = {fa.x, fa.y, fa.z, fa.w, fb.x, fb.y, fb.z, fb.w};
        const float* wr = NW1 + (size_t)kb * 8 * 64;
#pragma unroll
        for (int kk = 0; kk < 8; ++kk)
#pragma unroll
            for (int c = 0; c < 64; ++c)
                acc[c] = fmaf(fv[kk], wr[kk * 64 + c], acc[c]);
    }

    float t1[64];
#pragma unroll
    for (int c = 0; c < 64; ++c) t1[c] = silu_f(acc[c]);

    float acc2[64];
    MM64(acc2, t1, NW2, NB2)

    float* op = hn_out + (size_t)n * HDIM;
#pragma unroll
    for (int c4 = 0; c4 < 16; ++c4) {
        float4 v;
        v.x = acc2[c4 * 4 + 0]; v.y = acc2[c4 * 4 + 1];
        v.z = acc2[c4 * 4 + 2]; v.w = acc2[c4 * 4 + 3];
        *(float4*)(op + c4 * 4) = v;
    }

    // coordinate update (mean aggregation, zero for isolated nodes)
    const float inv = 1.0f / fmaxf(dg[n], 1.0f);
    x[3 * (size_t)n + 0] += xs[3 * (size_t)n + 0] * inv;
    x[3 * (size_t)n + 1] += xs[3 * (size_t)n + 1] * inv;
    x[3 * (size_t)n + 2] += xs[3 * (size_t)n + 2] * inv;
}

// ---------------------------------------------------------------------------
// BN stat partials: lane = channel, wave strides over rows (coalesced 256B).
// fp64 accumulation + native f64 atomics: avoids E[x^2]-mu^2 cancellation.
// ---------------------------------------------------------------------------
__global__ void __launch_bounds__(256) bn_stats(
    const float* __restrict__ hn, double* __restrict__ stats, int N)
{
    const int gw = (blockIdx.x * 256 + (int)threadIdx.x) >> 6;
    const int lane = threadIdx.x & 63;
    const int nw = (gridDim.x * 256) >> 6;
    double s = 0.0, q = 0.0;
    for (int r = gw; r < N; r += nw) {
        const double v = (double)hn[(size_t)r * HDIM + lane];
        s += v;
        q += v * v;
    }
    atomicAdd(&stats[lane], s);
    atomicAdd(&stats[64 + lane], q);
}

__global__ void bn_final(
    const double* __restrict__ stats, const float* __restrict__ gamma,
    const float* __restrict__ beta, float* __restrict__ ss, double invN)
{
    const int c = threadIdx.x; // 64 threads
    const double mu = stats[c] * invN;
    const double var = stats[64 + c] * invN - mu * mu;
    const float rstd = rsqrtf((float)var + 1e-5f);
    const float sc = gamma[c] * rstd;
    ss[c] = sc;
    ss[64 + c] = beta[c] - (float)mu * sc;
}

// h = relu(hn*scale + shift); out = h (l==0) or out += h (JK sum)
__global__ void __launch_bounds__(256) bn_apply(
    const float* __restrict__ hn, const float* __restrict__ ss,
    float* __restrict__ h, float* __restrict__ out, int n4, int accum)
{
    const int i = blockIdx.x * 256 + threadIdx.x;
    if (i >= n4) return;
    const int c4 = (i & 15) * 4;
    const float4 v = *(const float4*)(hn + (size_t)i * 4);
    float4 r;
    r.x = fmaxf(fmaf(v.x, ss[c4 + 0], ss[64 + c4 + 0]), 0.0f);
    r.y = fmaxf(fmaf(v.y, ss[c4 + 1], ss[64 + c4 + 1]), 0.0f);
    r.z = fmaxf(fmaf(v.z, ss[c4 + 2], ss[64 + c4 + 2]), 0.0f);
    r.w = fmaxf(fmaf(v.w, ss[c4 + 3], ss[64 + c4 + 3]), 0.0f);
    *(float4*)(h + (size_t)i * 4) = r;
    float4* op = (float4*)out + i;
    if (accum) {
        float4 o = *op;
        o.x += r.x; o.y += r.y; o.z += r.z; o.w += r.w;
        *op = o;
    } else {
        *op = r;
    }
}

// ---------------------------------------------------------------------------
extern "C" void kernel_launch(void* const* d_in, const int* in_sizes, int n_in,
                              void* d_out, int out_size, void* d_ws, size_t ws_size,
                              hipStream_t stream)
{
    const float* node_feat = (const float*)d_in[0];
    const float* pos       = (const float*)d_in[1];
    const float* edge_feat = (const float*)d_in[2];
    const int*   src       = (const int*)d_in[3];
    const int*   dst       = (const int*)d_in[4];
    const float* ew1 = (const float*)d_in[5];
    const float* eb1 = (const float*)d_in[6];
    const float* ew2 = (const float*)d_in[7];
    const float* eb2 = (const float*)d_in[8];
    const float* cw1 = (const float*)d_in[9];
    const float* cb1 = (const float*)d_in[10];
    const float* cw2 = (const float*)d_in[11];
    const float* nw1 = (const float*)d_in[12];
    const float* nb1 = (const float*)d_in[13];
    const float* nw2 = (const float*)d_in[14];
    const float* nb2 = (const float*)d_in[15];
    const float* gamma = (const float*)d_in[16];
    const float* beta  = (const float*)d_in[17];

    const int N = in_sizes[0] / HDIM;
    const int E = in_sizes[3];
    const int L = in_sizes[6] / HDIM; // eb1 is [L,64]

    // workspace carve-up (all segments well-aligned given sizes below)
    char* ws = (char*)d_ws;
    float* hbuf  = (float*)ws; ws += (size_t)N * HDIM * 4; // 10.24 MB
    float* xbuf  = (float*)ws; ws += (size_t)N * 3 * 4;    // 0.48 MB
    float* hno   = (float*)ws; ws += (size_t)N * HDIM * 4; // 10.24 MB
    float* xso   = (float*)ws; ws += (size_t)N * 3 * 4;    // 0.48 MB
    float* dgo   = (float*)ws; ws += (size_t)N * 4;        // 0.16 MB
    float* hnbuf = (float*)ws; ws += (size_t)N * HDIM * 4; // 10.24 MB
    double* stats = (double*)ws; ws += 128 * 8;
    float* ssbuf  = (float*)ws; ws += 128 * 4;

    hipMemcpyAsync(hbuf, node_feat, (size_t)N * HDIM * 4,
                   hipMemcpyDeviceToDevice, stream);
    hipMemcpyAsync(xbuf, pos, (size_t)N * 3 * 4,
                   hipMemcpyDeviceToDevice, stream);

    // degree is layer-invariant: count once
    hipMemsetAsync(dgo, 0, (size_t)N * 4, stream);
    deg_count<<<(E + 255) / 256, 256, 0, stream>>>(dst, dgo, E);

    for (int l = 0; l < L; ++l) {
        hipMemsetAsync(hno, 0, (size_t)N * HDIM * 4, stream);
        hipMemsetAsync(xso, 0, (size_t)N * 3 * 4, stream);
        hipMemsetAsync(stats, 0, 128 * 8, stream);

        egnn_edge<<<(E + 255) / 256, 256, 0, stream>>>(
            hbuf, xbuf, edge_feat, src, dst,
            ew1 + (size_t)l * 145 * 64, eb1 + (size_t)l * 64,
            ew2 + (size_t)l * 64 * 64,  eb2 + (size_t)l * 64,
            cw1 + (size_t)l * 64 * 64,  cb1 + (size_t)l * 64,
            cw2 + (size_t)l * 64,
            hno, xso, E);

        egnn_node<<<(N + 255) / 256, 256, 0, stream>>>(
            hbuf, hno, xso, dgo, xbuf,
            nw1 + (size_t)l * 128 * 64, nb1 + (size_t)l * 64,
            nw2 + (size_t)l * 64 * 64,  nb2 + (size_t)l * 64,
            hnbuf, N);

        bn_stats<<<256, 256, 0, stream>>>(hnbuf, stats, N);
        bn_final<<<1, 64, 0, stream>>>(stats, gamma + (size_t)l * 64,
                                       beta + (size_t)l * 64, ssbuf,
                                       1.0 / (double)N);
        bn_apply<<<(N * 16 + 255) / 256, 256, 0, stream>>>(
            hnbuf, ssbuf, hbuf, (float*)d_out, N * 16, l > 0);
    }
}

// Round 6
// 1894.146 us; speedup vs baseline: 2.9968x; 2.9968x over previous
//
#include <hip/hip_runtime.h>
#include <hip/hip_bf16.h>
#include <cstddef>

// EGNN on MI355X. fp32 (no fp32 MFMA on CDNA4 -> vector-ALU kernels).
// v2 edge kernel: per-thread-per-edge MLP kept (scalar weight loads), but all
// gathers/scatters go through LDS transposes so lane=channel => coalesced
// 64B transactions instead of 64x random 4-16B transactions per wave instr.
// BN stats in fp64 atomics. Degree hoisted out of the layer loop.

#define HDIM 64
#define DEDIM 16

__device__ __forceinline__ float silu_f(float v) {
    return v / (1.0f + __expf(-v));
}

// out[c] = B[c] + sum_k in[k] * W[k*64+c], fully unrolled (static reg indexing)
#define MM64(OUT, IN, W, B)                                                   \
    _Pragma("unroll") for (int c = 0; c < 64; ++c) OUT[c] = (B)[c];           \
    _Pragma("unroll") for (int k = 0; k < 64; ++k) {                          \
        const float tv_ = IN[k];                                              \
        _Pragma("unroll") for (int c = 0; c < 64; ++c)                        \
            OUT[c] = fmaf(tv_, (W)[k * 64 + c], OUT[c]);                      \
    }

// ---------------------------------------------------------------------------
__global__ void __launch_bounds__(256) deg_count(
    const int* __restrict__ dst, float* __restrict__ dgo, int E)
{
    const int e = blockIdx.x * 256 + threadIdx.x;
    if (e < E) atomicAdd(&dgo[dst[e]], 1.0f);
}

// ---------------------------------------------------------------------------
// Edge kernel v2. Block = 256 threads = 256 edges.
// f = [h_src(rows 0-63) | h_dst(64-127) | radial(128) | edge_feat(129-144)]
// ---------------------------------------------------------------------------
__global__ void __launch_bounds__(256) egnn_edge(
    const float* __restrict__ h, const float* __restrict__ x,
    const float* __restrict__ ef, const int* __restrict__ src,
    const int* __restrict__ dst,
    const float* __restrict__ W1, const float* __restrict__ B1,
    const float* __restrict__ W2, const float* __restrict__ B2,
    const float* __restrict__ C1, const float* __restrict__ CB1,
    const float* __restrict__ C2,
    float* __restrict__ hno, float* __restrict__ xso, int E)
{
    __shared__ float stage[256 * 17];   // 16-ch chunk, +1 pad -> <=2-way banks
    __shared__ float ldsXs[256 * 4];
    __shared__ float ldsXd[256 * 4];
    __shared__ int   sIdx[256];
    __shared__ int   dIdx[256];

    const int t  = threadIdx.x;
    const int eb = blockIdx.x * 256;
    const int e  = eb + t;
    const int lastE = E - 1;

    // ---- index stage (coalesced) ----
    {
        const int ee = (e < E) ? e : lastE;
        sIdx[t] = src[ee];
        dIdx[t] = dst[ee];
    }
    __syncthreads();

    // ---- position stage: 768 elements, q = i*256+t -> (edge q/3, comp q%3)
    // lanes cover consecutive q -> 12B-contiguous per edge (~21 edges/instr)
#pragma unroll
    for (int i = 0; i < 3; ++i) {
        const int q  = i * 256 + t;
        const int ed = q / 3;
        const int c  = q - ed * 3;
        ldsXs[ed * 4 + c] = x[(size_t)sIdx[ed] * 3 + c];
        ldsXd[ed * 4 + c] = x[(size_t)dIdx[ed] * 3 + c];
    }
    __syncthreads();

    const float dx0 = ldsXs[t * 4 + 0] - ldsXd[t * 4 + 0];
    const float dx1 = ldsXs[t * 4 + 1] - ldsXd[t * 4 + 1];
    const float dx2 = ldsXs[t * 4 + 2] - ldsXd[t * 4 + 2];
    const float radial = dx0 * dx0 + dx1 * dx1 + dx2 * dx2;
    const float rinv = 1.0f / (sqrtf(radial) + 1e-30f);

    float acc[64];
#pragma unroll
    for (int c = 0; c < 64; ++c) acc[c] = B1[c];

    // ---- h_src chunks: stage (lane=channel, 64B txns) then consume ----
#pragma unroll 1
    for (int kb = 0; kb < 4; ++kb) {
        __syncthreads();               // stage buffer free (prev consume done)
#pragma unroll
        for (int i = 0; i < 16; ++i) {
            const int ed = i * 16 + (t >> 4);
            const int ch = t & 15;
            stage[ed * 17 + ch] = h[(size_t)sIdx[ed] * HDIM + kb * 16 + ch];
        }
        __syncthreads();
#pragma unroll
        for (int j = 0; j < 16; ++j) {
            const float v = stage[t * 17 + j];
            const float* wr = W1 + (size_t)(kb * 16 + j) * 64;
#pragma unroll
            for (int c = 0; c < 64; ++c) acc[c] = fmaf(v, wr[c], acc[c]);
        }
    }

    // ---- h_dst chunks ----
#pragma unroll 1
    for (int kb = 0; kb < 4; ++kb) {
        __syncthreads();
#pragma unroll
        for (int i = 0; i < 16; ++i) {
            const int ed = i * 16 + (t >> 4);
            const int ch = t & 15;
            stage[ed * 17 + ch] = h[(size_t)dIdx[ed] * HDIM + kb * 16 + ch];
        }
        __syncthreads();
#pragma unroll
        for (int j = 0; j < 16; ++j) {
            const float v = stage[t * 17 + j];
            const float* wr = W1 + (size_t)(64 + kb * 16 + j) * 64;
#pragma unroll
            for (int c = 0; c < 64; ++c) acc[c] = fmaf(v, wr[c], acc[c]);
        }
    }

    // ---- edge_feat chunk (fully contiguous 256B/instr streams) ----
    {
        __syncthreads();
#pragma unroll
        for (int i = 0; i < 16; ++i) {
            const int ed = i * 16 + (t >> 4);
            const int ch = t & 15;
            const int ee = (eb + ed < E) ? (eb + ed) : lastE;
            stage[ed * 17 + ch] = ef[(size_t)ee * DEDIM + ch];
        }
        __syncthreads();
#pragma unroll
        for (int j = 0; j < 16; ++j) {
            const float v = stage[t * 17 + j];
            const float* wr = W1 + (size_t)(129 + j) * 64;
#pragma unroll
            for (int c = 0; c < 64; ++c) acc[c] = fmaf(v, wr[c], acc[c]);
        }
    }

    // ---- radial row (128) ----
    {
        const float* wr = W1 + (size_t)128 * 64;
#pragma unroll
        for (int c = 0; c < 64; ++c) acc[c] = fmaf(radial, wr[c], acc[c]);
    }

    // ---- rest of edge MLP (register-resident) ----
    float t1[64];
#pragma unroll
    for (int c = 0; c < 64; ++c) t1[c] = silu_f(acc[c]);

    float acc2[64];
    MM64(acc2, t1, W2, B2)
    float mh[64];
#pragma unroll
    for (int c = 0; c < 64; ++c) mh[c] = silu_f(acc2[c]);

    float acc3[64];
    MM64(acc3, mh, C1, CB1)
#pragma unroll
    for (int c = 0; c < 64; ++c) acc3[c] = silu_f(acc3[c]);

    float coef = 0.0f;
#pragma unroll
    for (int c = 0; c < 64; ++c) coef = fmaf(acc3[c], C2[c], coef);

    // ---- coalesced x scatter ----
    const float cr = coef * rinv;
    ldsXs[t * 4 + 0] = cr * dx0;
    ldsXs[t * 4 + 1] = cr * dx1;
    ldsXs[t * 4 + 2] = cr * dx2;
    __syncthreads();
#pragma unroll
    for (int i = 0; i < 3; ++i) {
        const int q  = i * 256 + t;
        const int ed = q / 3;
        const int c  = q - ed * 3;
        if (eb + ed < E)
            atomicAdd(&xso[(size_t)dIdx[ed] * 3 + c], ldsXs[ed * 4 + c]);
    }

    // ---- coalesced h scatter: 4 chunks of 16 channels ----
#pragma unroll 1
    for (int cb = 0; cb < 4; ++cb) {
        __syncthreads();               // stage free (prev chunk's atomics read)
#pragma unroll
        for (int j = 0; j < 16; ++j) stage[t * 17 + j] = mh[cb * 16 + j];
        __syncthreads();
#pragma unroll
        for (int i = 0; i < 16; ++i) {
            const int ed = i * 16 + (t >> 4);
            const int ch = t & 15;
            if (eb + ed < E)
                atomicAdd(&hno[(size_t)dIdx[ed] * HDIM + cb * 16 + ch],
                          stage[ed * 17 + ch]);
        }
    }
}

// ---------------------------------------------------------------------------
// Node kernel: hn = silu([h|h_neigh]@NW1+NB1)@NW2+NB2 ; x += x_sum/max(deg,1)
// ---------------------------------------------------------------------------
__global__ void __launch_bounds__(256) egnn_node(
    const float* __restrict__ h, const float* __restrict__ hnb,
    const float* __restrict__ xs, const float* __restrict__ dg,
    float* __restrict__ x,
    const float* __restrict__ NW1, const float* __restrict__ NB1,
    const float* __restrict__ NW2, const float* __restrict__ NB2,
    float* __restrict__ hn_out, int N)
{
    const int n = blockIdx.x * 256 + threadIdx.x;
    if (n >= N) return;

    float acc[64];
#pragma unroll
    for (int c = 0; c < 64; ++c) acc[c] = NB1[c];

    const float* hp = h + (size_t)n * HDIM;
    const float* gp = hnb + (size_t)n * HDIM;
#pragma unroll 1
    for (int kb = 0; kb < 16; ++kb) {
        const float* fp = (kb < 8) ? (hp + kb * 8) : (gp + (kb - 8) * 8);
        const float4 fa = *(const float4*)fp;
        const float4 fb = *(const float4*)(fp + 4);
        const float fv[8] = {fa.x, fa.y, fa.z, fa.w, fb.x, fb.y, fb.z, fb.w};
        const float* wr = NW1 + (size_t)kb * 8 * 64;
#pragma unroll
        for (int kk = 0; kk < 8; ++kk)
#pragma unroll
            for (int c = 0; c < 64; ++c)
                acc[c] = fmaf(fv[kk], wr[kk * 64 + c], acc[c]);
    }

    float t1[64];
#pragma unroll
    for (int c = 0; c < 64; ++c) t1[c] = silu_f(acc[c]);

    float acc2[64];
    MM64(acc2, t1, NW2, NB2)

    float* op = hn_out + (size_t)n * HDIM;
#pragma unroll
    for (int c4 = 0; c4 < 16; ++c4) {
        float4 v;
        v.x = acc2[c4 * 4 + 0]; v.y = acc2[c4 * 4 + 1];
        v.z = acc2[c4 * 4 + 2]; v.w = acc2[c4 * 4 + 3];
        *(float4*)(op + c4 * 4) = v;
    }

    const float inv = 1.0f / fmaxf(dg[n], 1.0f);
    x[3 * (size_t)n + 0] += xs[3 * (size_t)n + 0] * inv;
    x[3 * (size_t)n + 1] += xs[3 * (size_t)n + 1] * inv;
    x[3 * (size_t)n + 2] += xs[3 * (size_t)n + 2] * inv;
}

// ---------------------------------------------------------------------------
__global__ void __launch_bounds__(256) bn_stats(
    const float* __restrict__ hn, double* __restrict__ stats, int N)
{
    const int gw = (blockIdx.x * 256 + (int)threadIdx.x) >> 6;
    const int lane = threadIdx.x & 63;
    const int nw = (gridDim.x * 256) >> 6;
    double s = 0.0, q = 0.0;
    for (int r = gw; r < N; r += nw) {
        const double v = (double)hn[(size_t)r * HDIM + lane];
        s += v;
        q += v * v;
    }
    atomicAdd(&stats[lane], s);
    atomicAdd(&stats[64 + lane], q);
}

__global__ void bn_final(
    const double* __restrict__ stats, const float* __restrict__ gamma,
    const float* __restrict__ beta, float* __restrict__ ss, double invN)
{
    const int c = threadIdx.x; // 64 threads
    const double mu = stats[c] * invN;
    const double var = stats[64 + c] * invN - mu * mu;
    const float rstd = rsqrtf((float)var + 1e-5f);
    const float sc = gamma[c] * rstd;
    ss[c] = sc;
    ss[64 + c] = beta[c] - (float)mu * sc;
}

__global__ void __launch_bounds__(256) bn_apply(
    const float* __restrict__ hn, const float* __restrict__ ss,
    float* __restrict__ h, float* __restrict__ out, int n4, int accum)
{
    const int i = blockIdx.x * 256 + threadIdx.x;
    if (i >= n4) return;
    const int c4 = (i & 15) * 4;
    const float4 v = *(const float4*)(hn + (size_t)i * 4);
    float4 r;
    r.x = fmaxf(fmaf(v.x, ss[c4 + 0], ss[64 + c4 + 0]), 0.0f);
    r.y = fmaxf(fmaf(v.y, ss[c4 + 1], ss[64 + c4 + 1]), 0.0f);
    r.z = fmaxf(fmaf(v.z, ss[c4 + 2], ss[64 + c4 + 2]), 0.0f);
    r.w = fmaxf(fmaf(v.w, ss[c4 + 3], ss[64 + c4 + 3]), 0.0f);
    *(float4*)(h + (size_t)i * 4) = r;
    float4* op = (float4*)out + i;
    if (accum) {
        float4 o = *op;
        o.x += r.x; o.y += r.y; o.z += r.z; o.w += r.w;
        *op = o;
    } else {
        *op = r;
    }
}

// ---------------------------------------------------------------------------
extern "C" void kernel_launch(void* const* d_in, const int* in_sizes, int n_in,
                              void* d_out, int out_size, void* d_ws, size_t ws_size,
                              hipStream_t stream)
{
    const float* node_feat = (const float*)d_in[0];
    const float* pos       = (const float*)d_in[1];
    const float* edge_feat = (const float*)d_in[2];
    const int*   src       = (const int*)d_in[3];
    const int*   dst       = (const int*)d_in[4];
    const float* ew1 = (const float*)d_in[5];
    const float* eb1 = (const float*)d_in[6];
    const float* ew2 = (const float*)d_in[7];
    const float* eb2 = (const float*)d_in[8];
    const float* cw1 = (const float*)d_in[9];
    const float* cb1 = (const float*)d_in[10];
    const float* cw2 = (const float*)d_in[11];
    const float* nw1 = (const float*)d_in[12];
    const float* nb1 = (const float*)d_in[13];
    const float* nw2 = (const float*)d_in[14];
    const float* nb2 = (const float*)d_in[15];
    const float* gamma = (const float*)d_in[16];
    const float* beta  = (const float*)d_in[17];

    const int N = in_sizes[0] / HDIM;
    const int E = in_sizes[3];
    const int L = in_sizes[6] / HDIM; // eb1 is [L,64]

    char* ws = (char*)d_ws;
    float* hbuf  = (float*)ws; ws += (size_t)N * HDIM * 4;
    float* xbuf  = (float*)ws; ws += (size_t)N * 3 * 4;
    float* hno   = (float*)ws; ws += (size_t)N * HDIM * 4;
    float* xso   = (float*)ws; ws += (size_t)N * 3 * 4;
    float* dgo   = (float*)ws; ws += (size_t)N * 4;
    float* hnbuf = (float*)ws; ws += (size_t)N * HDIM * 4;
    double* stats = (double*)ws; ws += 128 * 8;
    float* ssbuf  = (float*)ws; ws += 128 * 4;

    hipMemcpyAsync(hbuf, node_feat, (size_t)N * HDIM * 4,
                   hipMemcpyDeviceToDevice, stream);
    hipMemcpyAsync(xbuf, pos, (size_t)N * 3 * 4,
                   hipMemcpyDeviceToDevice, stream);

    hipMemsetAsync(dgo, 0, (size_t)N * 4, stream);
    deg_count<<<(E + 255) / 256, 256, 0, stream>>>(dst, dgo, E);

    for (int l = 0; l < L; ++l) {
        hipMemsetAsync(hno, 0, (size_t)N * HDIM * 4, stream);
        hipMemsetAsync(xso, 0, (size_t)N * 3 * 4, stream);
        hipMemsetAsync(stats, 0, 128 * 8, stream);

        egnn_edge<<<(E + 255) / 256, 256, 0, stream>>>(
            hbuf, xbuf, edge_feat, src, dst,
            ew1 + (size_t)l * 145 * 64, eb1 + (size_t)l * 64,
            ew2 + (size_t)l * 64 * 64,  eb2 + (size_t)l * 64,
            cw1 + (size_t)l * 64 * 64,  cb1 + (size_t)l * 64,
            cw2 + (size_t)l * 64,
            hno, xso, E);

        egnn_node<<<(N + 255) / 256, 256, 0, stream>>>(
            hbuf, hno, xso, dgo, xbuf,
            nw1 + (size_t)l * 128 * 64, nb1 + (size_t)l * 64,
            nw2 + (size_t)l * 64 * 64,  nb2 + (size_t)l * 64,
            hnbuf, N);

        bn_stats<<<256, 256, 0, stream>>>(hnbuf, stats, N);
        bn_final<<<1, 64, 0, stream>>>(stats, gamma + (size_t)l * 64,
                                       beta + (size_t)l * 64, ssbuf,
                                       1.0 / (double)N);
        bn_apply<<<(N * 16 + 255) / 256, 256, 0, stream>>>(
            hnbuf, ssbuf, hbuf, (float*)d_out, N * 16, l > 0);
    }
}

// Round 11
// 1499.928 us; speedup vs baseline: 3.7844x; 1.2628x over previous
//
#include <hip/hip_runtime.h>
#include <hip/hip_bf16.h>
#include <cstddef>

// EGNN on MI355X. fp32 (no fp32 MFMA on CDNA4 -> vector-ALU kernels).
// v3 edge kernel: barrier-free per-wave LDS staging (wave64 lockstep + DS
// in-order per wave; explicit lgkmcnt(0)+sched_barrier(0) for cross-lane
// hand-off), register prefetch of the next gather chunk under the current
// consume, and rolled consume loops (I$-sized body, wave-uniform weight rows).
// BN stats in fp64 atomics. Degree hoisted out of the layer loop.

#define HDIM 64
#define DEDIM 16

__device__ __forceinline__ float silu_f(float v) {
    return v / (1.0f + __expf(-v));
}

// cross-lane LDS hand-off fence (per-wave; no s_barrier):
#define WAITLGKM() do { asm volatile("s_waitcnt lgkmcnt(0)" ::: "memory"); \
                        __builtin_amdgcn_sched_barrier(0); } while (0)

// ---------------------------------------------------------------------------
__global__ void __launch_bounds__(256) deg_count(
    const int* __restrict__ dst, float* __restrict__ dgo, int E)
{
    const int e = blockIdx.x * 256 + threadIdx.x;
    if (e < E) atomicAdd(&dgo[dst[e]], 1.0f);
}

// ---------------------------------------------------------------------------
// Edge kernel v3. Block = 256 threads = 4 independent waves x 64 edges.
// f = [h_src(rows 0-63) | h_dst(64-127) | radial(128) | edge_feat(129-144)]
// ---------------------------------------------------------------------------
__global__ void __launch_bounds__(256, 3) egnn_edge(
    const float* __restrict__ h, const float* __restrict__ x,
    const float* __restrict__ ef, const int* __restrict__ src,
    const int* __restrict__ dst,
    const float* __restrict__ W1, const float* __restrict__ B1,
    const float* __restrict__ W2, const float* __restrict__ B2,
    const float* __restrict__ C1, const float* __restrict__ CB1,
    const float* __restrict__ C2,
    float* __restrict__ hno, float* __restrict__ xso, int E)
{
    __shared__ float stageS[4][64 * 17];   // per-wave 64-edge x 16-ch (+1 pad)
    __shared__ int   iS[4][64];
    __shared__ int   iD[4][64];

    const int t  = threadIdx.x;
    const int w  = t >> 6;
    const int l  = t & 63;
    const int eb = blockIdx.x * 256 + w * 64;   // this wave's first edge
    const int lastE = E - 1;

    float* stW = stageS[w];
    int*   sW  = iS[w];
    int*   dW  = iD[w];

    // ---- own-lane indices + geometry (x tables small & L2-hot) ----
    const int eOwn = (eb + l < E) ? (eb + l) : lastE;
    const int sOwn = src[eOwn];
    const int dOwn = dst[eOwn];
    sW[l] = sOwn;
    dW[l] = dOwn;

    const float dx0 = x[3 * sOwn + 0] - x[3 * dOwn + 0];
    const float dx1 = x[3 * sOwn + 1] - x[3 * dOwn + 1];
    const float dx2 = x[3 * sOwn + 2] - x[3 * dOwn + 2];
    const float radial = dx0 * dx0 + dx1 * dx1 + dx2 * dx2;
    const float rinv = 1.0f / (sqrtf(radial) + 1e-30f);

    WAITLGKM();   // publish sW/dW to all lanes of this wave

    // per-lane gather byte-offsets (32-bit; tables < 2 GB)
    int voffS[16], voffD[16];
#pragma unroll
    for (int i = 0; i < 16; ++i) {
        const int ed = i * 4 + (l >> 4);
        voffS[i] = sW[ed] * (HDIM * 4) + (l & 15) * 4;
    }

    float pf[16];
    // prefetch src chunk 0
#pragma unroll
    for (int i = 0; i < 16; ++i)
        pf[i] = *(const float*)((const char*)h + (size_t)(unsigned)voffS[i]);

    float acc[64];
#pragma unroll
    for (int c = 0; c < 64; ++c) acc[c] = B1[c];

#define DSW()                                                                 \
    _Pragma("unroll") for (int i = 0; i < 16; ++i) {                          \
        const int ed = i * 4 + (l >> 4);                                      \
        stW[ed * 17 + (l & 15)] = pf[i];                                      \
    }
#define PFLOAD(BASE, VOFF, BOFF)                                              \
    _Pragma("unroll") for (int i = 0; i < 16; ++i)                            \
        pf[i] = *(const float*)((const char*)(BASE) +                         \
                                (size_t)(unsigned)(VOFF)[i] + (BOFF));
#define CONS16(ACC, ROWS) do { WAITLGKM();                                    \
    _Pragma("unroll 1") for (int j = 0; j < 16; ++j) {                        \
        const float v = stW[l * 17 + j];                                      \
        const float* wr = (ROWS) + (size_t)((unsigned)j * 64u);               \
        _Pragma("unroll") for (int c = 0; c < 64; ++c)                        \
            ACC[c] = fmaf(v, wr[c], ACC[c]);                                  \
    } } while (0)

    // ---- W1: h_src rows 0..63 ----
    DSW(); PFLOAD(h, voffS,  64); CONS16(acc, W1 +   0 * 64);
    DSW(); PFLOAD(h, voffS, 128); CONS16(acc, W1 +  16 * 64);
    DSW(); PFLOAD(h, voffS, 192); CONS16(acc, W1 +  32 * 64);
#pragma unroll
    for (int i = 0; i < 16; ++i) {
        const int ed = i * 4 + (l >> 4);
        voffD[i] = dW[ed] * (HDIM * 4) + (l & 15) * 4;
    }
    DSW(); PFLOAD(h, voffD,   0); CONS16(acc, W1 +  48 * 64);
    // ---- W1: h_dst rows 64..127 ----
    DSW(); PFLOAD(h, voffD,  64); CONS16(acc, W1 +  64 * 64);
    DSW(); PFLOAD(h, voffD, 128); CONS16(acc, W1 +  80 * 64);
    DSW(); PFLOAD(h, voffD, 192); CONS16(acc, W1 +  96 * 64);
    int voffE[16];
#pragma unroll
    for (int i = 0; i < 16; ++i) {
        const int ed = i * 4 + (l >> 4);
        const int ee = (eb + ed < E) ? (eb + ed) : lastE;
        voffE[i] = ee * (DEDIM * 4) + (l & 15) * 4;
    }
    DSW(); PFLOAD(ef, voffE,  0); CONS16(acc, W1 + 112 * 64);
    // ---- W1: edge_feat rows 129..144 ----
    DSW();                        CONS16(acc, W1 + 129 * 64);
    // ---- W1: radial row 128 ----
    {
        const float* wr = W1 + (size_t)128 * 64;
#pragma unroll
        for (int c = 0; c < 64; ++c) acc[c] = fmaf(radial, wr[c], acc[c]);
    }

    // ---- t1 = silu(acc); acc2 = t1 @ W2 + B2 (activations via LDS chunks) --
#define TCHUNK(SRCACC, KB) do { WAITLGKM();                                   \
    _Pragma("unroll") for (int j = 0; j < 16; ++j)                            \
        stW[l * 17 + j] = silu_f(SRCACC[(KB) * 16 + j]);                      \
    } while (0)

    float acc2[64];
#pragma unroll
    for (int c = 0; c < 64; ++c) acc2[c] = B2[c];
    TCHUNK(acc, 0); CONS16(acc2, W2 +  0 * 64);
    TCHUNK(acc, 1); CONS16(acc2, W2 + 16 * 64);
    TCHUNK(acc, 2); CONS16(acc2, W2 + 32 * 64);
    TCHUNK(acc, 3); CONS16(acc2, W2 + 48 * 64);

    // ---- mh = silu(acc2); acc3 = mh @ C1 + CB1 ; scatter mh to hno ----
#define HSCAT(KB)                                                             \
    _Pragma("unroll 1") for (int i = 0; i < 16; ++i) {                        \
        const int ed = i * 4 + (l >> 4);                                      \
        const int ch = l & 15;                                                \
        if (eb + ed < E)                                                      \
            atomicAdd(&hno[(size_t)dW[ed] * HDIM + (KB) * 16 + ch],           \
                      stW[ed * 17 + ch]);                                     \
    }

    float acc3[64];
#pragma unroll
    for (int c = 0; c < 64; ++c) acc3[c] = CB1[c];
    TCHUNK(acc2, 0); CONS16(acc3, C1 +  0 * 64); HSCAT(0);
    TCHUNK(acc2, 1); CONS16(acc3, C1 + 16 * 64); HSCAT(1);
    TCHUNK(acc2, 2); CONS16(acc3, C1 + 32 * 64); HSCAT(2);
    TCHUNK(acc2, 3); CONS16(acc3, C1 + 48 * 64); HSCAT(3);

    // ---- coef = silu(acc3) . C2 ; x scatter (own lane) ----
    float coef = 0.0f;
#pragma unroll
    for (int c = 0; c < 64; ++c) coef = fmaf(silu_f(acc3[c]), C2[c], coef);

    if (eb + l < E) {
        const float cr = coef * rinv;
        atomicAdd(&xso[3 * (size_t)dOwn + 0], cr * dx0);
        atomicAdd(&xso[3 * (size_t)dOwn + 1], cr * dx1);
        atomicAdd(&xso[3 * (size_t)dOwn + 2], cr * dx2);
    }
#undef DSW
#undef PFLOAD
#undef CONS16
#undef TCHUNK
#undef HSCAT
}

// ---------------------------------------------------------------------------
// Node kernel: hn = silu([h|h_neigh]@NW1+NB1)@NW2+NB2 ; x += x_sum/max(deg,1)
// ---------------------------------------------------------------------------
#define MM64(OUT, IN, W, B)                                                   \
    _Pragma("unroll") for (int c = 0; c < 64; ++c) OUT[c] = (B)[c];           \
    _Pragma("unroll") for (int k = 0; k < 64; ++k) {                          \
        const float tv_ = IN[k];                                              \
        _Pragma("unroll") for (int c = 0; c < 64; ++c)                        \
            OUT[c] = fmaf(tv_, (W)[k * 64 + c], OUT[c]);                      \
    }

__global__ void __launch_bounds__(256) egnn_node(
    const float* __restrict__ h, const float* __restrict__ hnb,
    const float* __restrict__ xs, const float* __restrict__ dg,
    float* __restrict__ x,
    const float* __restrict__ NW1, const float* __restrict__ NB1,
    const float* __restrict__ NW2, const float* __restrict__ NB2,
    float* __restrict__ hn_out, int N)
{
    const int n = blockIdx.x * 256 + threadIdx.x;
    if (n >= N) return;

    float acc[64];
#pragma unroll
    for (int c = 0; c < 64; ++c) acc[c] = NB1[c];

    const float* hp = h + (size_t)n * HDIM;
    const float* gp = hnb + (size_t)n * HDIM;
#pragma unroll 1
    for (int kb = 0; kb < 16; ++kb) {
        const float* fp = (kb < 8) ? (hp + kb * 8) : (gp + (kb - 8) * 8);
        const float4 fa = *(const float4*)fp;
        const float4 fb = *(const float4*)(fp + 4);
        const float fv[8] = {fa.x, fa.y, fa.z, fa.w, fb.x, fb.y, fb.z, fb.w};
        const float* wr = NW1 + (size_t)kb * 8 * 64;
#pragma unroll
        for (int kk = 0; kk < 8; ++kk)
#pragma unroll
            for (int c = 0; c < 64; ++c)
                acc[c] = fmaf(fv[kk], wr[kk * 64 + c], acc[c]);
    }

    float t1[64];
#pragma unroll
    for (int c = 0; c < 64; ++c) t1[c] = silu_f(acc[c]);

    float acc2[64];
    MM64(acc2, t1, NW2, NB2)

    float* op = hn_out + (size_t)n * HDIM;
#pragma unroll
    for (int c4 = 0; c4 < 16; ++c4) {
        float4 v;
        v.x = acc2[c4 * 4 + 0]; v.y = acc2[c4 * 4 + 1];
        v.z = acc2[c4 * 4 + 2]; v.w = acc2[c4 * 4 + 3];
        *(float4*)(op + c4 * 4) = v;
    }

    const float inv = 1.0f / fmaxf(dg[n], 1.0f);
    x[3 * (size_t)n + 0] += xs[3 * (size_t)n + 0] * inv;
    x[3 * (size_t)n + 1] += xs[3 * (size_t)n + 1] * inv;
    x[3 * (size_t)n + 2] += xs[3 * (size_t)n + 2] * inv;
}

// ---------------------------------------------------------------------------
__global__ void __launch_bounds__(256) bn_stats(
    const float* __restrict__ hn, double* __restrict__ stats, int N)
{
    const int gw = (blockIdx.x * 256 + (int)threadIdx.x) >> 6;
    const int lane = threadIdx.x & 63;
    const int nw = (gridDim.x * 256) >> 6;
    double s = 0.0, q = 0.0;
    for (int r = gw; r < N; r += nw) {
        const double v = (double)hn[(size_t)r * HDIM + lane];
        s += v;
        q += v * v;
    }
    atomicAdd(&stats[lane], s);
    atomicAdd(&stats[64 + lane], q);
}

__global__ void bn_final(
    const double* __restrict__ stats, const float* __restrict__ gamma,
    const float* __restrict__ beta, float* __restrict__ ss, double invN)
{
    const int c = threadIdx.x; // 64 threads
    const double mu = stats[c] * invN;
    const double var = stats[64 + c] * invN - mu * mu;
    const float rstd = rsqrtf((float)var + 1e-5f);
    const float sc = gamma[c] * rstd;
    ss[c] = sc;
    ss[64 + c] = beta[c] - (float)mu * sc;
}

__global__ void __launch_bounds__(256) bn_apply(
    const float* __restrict__ hn, const float* __restrict__ ss,
    float* __restrict__ h, float* __restrict__ out, int n4, int accum)
{
    const int i = blockIdx.x * 256 + threadIdx.x;
    if (i >= n4) return;
    const int c4 = (i & 15) * 4;
    const float4 v = *(const float4*)(hn + (size_t)i * 4);
    float4 r;
    r.x = fmaxf(fmaf(v.x, ss[c4 + 0], ss[64 + c4 + 0]), 0.0f);
    r.y = fmaxf(fmaf(v.y, ss[c4 + 1], ss[64 + c4 + 1]), 0.0f);
    r.z = fmaxf(fmaf(v.z, ss[c4 + 2], ss[64 + c4 + 2]), 0.0f);
    r.w = fmaxf(fmaf(v.w, ss[c4 + 3], ss[64 + c4 + 3]), 0.0f);
    *(float4*)(h + (size_t)i * 4) = r;
    float4* op = (float4*)out + i;
    if (accum) {
        float4 o = *op;
        o.x += r.x; o.y += r.y; o.z += r.z; o.w += r.w;
        *op = o;
    } else {
        *op = r;
    }
}

// ---------------------------------------------------------------------------
extern "C" void kernel_launch(void* const* d_in, const int* in_sizes, int n_in,
                              void* d_out, int out_size, void* d_ws, size_t ws_size,
                              hipStream_t stream)
{
    const float* node_feat = (const float*)d_in[0];
    const float* pos       = (const float*)d_in[1];
    const float* edge_feat = (const float*)d_in[2];
    const int*   src       = (const int*)d_in[3];
    const int*   dst       = (const int*)d_in[4];
    const float* ew1 = (const float*)d_in[5];
    const float* eb1 = (const float*)d_in[6];
    const float* ew2 = (const float*)d_in[7];
    const float* eb2 = (const float*)d_in[8];
    const float* cw1 = (const float*)d_in[9];
    const float* cb1 = (const float*)d_in[10];
    const float* cw2 = (const float*)d_in[11];
    const float* nw1 = (const float*)d_in[12];
    const float* nb1 = (const float*)d_in[13];
    const float* nw2 = (const float*)d_in[14];
    const float* nb2 = (const float*)d_in[15];
    const float* gamma = (const float*)d_in[16];
    const float* beta  = (const float*)d_in[17];

    const int N = in_sizes[0] / HDIM;
    const int E = in_sizes[3];
    const int L = in_sizes[6] / HDIM; // eb1 is [L,64]

    char* ws = (char*)d_ws;
    float* hbuf  = (float*)ws; ws += (size_t)N * HDIM * 4;
    float* xbuf  = (float*)ws; ws += (size_t)N * 3 * 4;
    float* hno   = (float*)ws; ws += (size_t)N * HDIM * 4;
    float* xso   = (float*)ws; ws += (size_t)N * 3 * 4;
    float* dgo   = (float*)ws; ws += (size_t)N * 4;
    float* hnbuf = (float*)ws; ws += (size_t)N * HDIM * 4;
    double* stats = (double*)ws; ws += 128 * 8;
    float* ssbuf  = (float*)ws; ws += 128 * 4;

    hipMemcpyAsync(hbuf, node_feat, (size_t)N * HDIM * 4,
                   hipMemcpyDeviceToDevice, stream);
    hipMemcpyAsync(xbuf, pos, (size_t)N * 3 * 4,
                   hipMemcpyDeviceToDevice, stream);

    hipMemsetAsync(dgo, 0, (size_t)N * 4, stream);
    deg_count<<<(E + 255) / 256, 256, 0, stream>>>(dst, dgo, E);

    for (int l = 0; l < L; ++l) {
        hipMemsetAsync(hno, 0, (size_t)N * HDIM * 4, stream);
        hipMemsetAsync(xso, 0, (size_t)N * 3 * 4, stream);
        hipMemsetAsync(stats, 0, 128 * 8, stream);

        egnn_edge<<<(E + 255) / 256, 256, 0, stream>>>(
            hbuf, xbuf, edge_feat, src, dst,
            ew1 + (size_t)l * 145 * 64, eb1 + (size_t)l * 64,
            ew2 + (size_t)l * 64 * 64,  eb2 + (size_t)l * 64,
            cw1 + (size_t)l * 64 * 64,  cb1 + (size_t)l * 64,
            cw2 + (size_t)l * 64,
            hno, xso, E);

        egnn_node<<<(N + 255) / 256, 256, 0, stream>>>(
            hbuf, hno, xso, dgo, xbuf,
            nw1 + (size_t)l * 128 * 64, nb1 + (size_t)l * 64,
            nw2 + (size_t)l * 64 * 64,  nb2 + (size_t)l * 64,
            hnbuf, N);

        bn_stats<<<256, 256, 0, stream>>>(hnbuf, stats, N);
        bn_final<<<1, 64, 0, stream>>>(stats, gamma + (size_t)l * 64,
                                       beta + (size_t)l * 64, ssbuf,
                                       1.0 / (double)N);
        bn_apply<<<(N * 16 + 255) / 256, 256, 0, stream>>>(
            hnbuf, ssbuf, hbuf, (float*)d_out, N * 16, l > 0);
    }
}